// Round 6
// baseline (380.847 us; speedup 1.0000x reference)
//
#include <hip/hip_runtime.h>

// ---------------------------------------------------------------------------
// Kernel 0: replicate the reference's fp32 cas table EXACTLY:
//   ang  = fp32( fp32(2*pi/128) * fp32(f*m) )   (UNREDUCED angle, up to ~792)
//   cas  = fp32(cos(ang)) + fp32(sin(ang))      (per-term fp32 rounding)
// Must match the reference's table (a more accurate table FAILS: cosphi =
// C/hypot amplifies table mismatch at small-hypot pixels; measured round 2).
// ---------------------------------------------------------------------------
__global__ void k_cas(float* __restrict__ casf) {
    int f = blockIdx.x, m = threadIdx.x;
    const float SC = (float)(6.283185307179586 / 128.0);  // fp32(2*pi/128)
    float ang = SC * (float)(f * m);                      // fp32 multiply, unreduced
    double a = (double)ang;
    float cv = (float)cos(a);
    float sv = (float)sin(a);
    casf[f * 128 + m] = cv + sv;                          // fp32 add
}

// ---------------------------------------------------------------------------
// Kernel 1: per (image, g-quarter): C = cas*X*cas, S = cas*Xf*cas restricted
// to 32 spectral columns G0..G0+31.
//   Phase 1: T1[m,g] = sum_k X[m,k] cas[k,g]
//            T2[127-m,g] = sum_k X[m,k] cas[127-k,g]   (k/(127-k) pairing)
//   Phase 2: C[f,g] = sum_m cas[f,m] T1[m,g];  S likewise from T2.
//   cosphi = C*rsqrt(C^2+S^2) -> d_out (scratch); corners of C -> cp1/cp2.
// cas is read straight from global (L1-resident, one 128B line per wave read)
// so LDS = T1+T2 = 32KB exactly -> 5 blocks/CU = 20 waves/CU (occupancy was
// the round-5 limiter: 29% occ, VALUBusy 68%).
// ---------------------------------------------------------------------------
__global__ __launch_bounds__(256, 5) void k_dht(
    const float* __restrict__ xg,
    const float* __restrict__ cas,
    float* __restrict__ cosphi,
    float* __restrict__ cp1,
    float* __restrict__ cp2)
{
    __shared__ float T1s[128 * 32];   // 16 KB
    __shared__ float T2s[128 * 32];   // 16 KB

    const int img = blockIdx.x;
    const int G0  = blockIdx.y * 32;
    const float* X = xg + (size_t)img * 16384;
    const int t = threadIdx.x;

    const int rowg = t >> 3;               // 0..31
    const int colg = t & 7;                // 0..7
    const int r0 = rowg * 4;               // 4 rows per thread
    const int j0 = colg * 4;               // 4 cols per thread

    // ---- phase 1 ----
    float R1[4][4], R2[4][4];
    #pragma unroll
    for (int i = 0; i < 4; ++i)
        #pragma unroll
        for (int l = 0; l < 4; ++l) { R1[i][l] = 0.f; R2[i][l] = 0.f; }

    for (int kk = 0; kk < 64; kk += 4) {
        float4 Xa[4], Xb[4];
        #pragma unroll
        for (int i = 0; i < 4; ++i) {
            Xa[i] = *(const float4*)&X[(r0 + i) * 128 + kk];          // cols kk..kk+3
            Xb[i] = *(const float4*)&X[(r0 + i) * 128 + 124 - kk];    // cols 124-kk..127-kk
        }
        #pragma unroll
        for (int u = 0; u < 4; ++u) {
            const int k = kk + u;
            float4 c1 = *(const float4*)&cas[k * 128 + G0 + j0];          // cas[k][g]
            float4 c2 = *(const float4*)&cas[(127 - k) * 128 + G0 + j0];  // cas[127-k][g]
            #pragma unroll
            for (int i = 0; i < 4; ++i) {
                float x1 = ((const float*)&Xa[i])[u];                 // X[r][k]
                float x2 = ((const float*)&Xb[i])[3 - u];             // X[r][127-k]
                #pragma unroll
                for (int l = 0; l < 4; ++l) {
                    float c1l = ((const float*)&c1)[l];
                    float c2l = ((const float*)&c2)[l];
                    R1[i][l] = fmaf(x1, c1l, R1[i][l]);
                    R1[i][l] = fmaf(x2, c2l, R1[i][l]);
                    R2[i][l] = fmaf(x1, c2l, R2[i][l]);
                    R2[i][l] = fmaf(x2, c1l, R2[i][l]);
                }
            }
        }
    }
    #pragma unroll
    for (int i = 0; i < 4; ++i) {
        float4 v1 = { R1[i][0], R1[i][1], R1[i][2], R1[i][3] };
        float4 v2 = { R2[i][0], R2[i][1], R2[i][2], R2[i][3] };
        *(float4*)&T1s[(r0 + i) * 32 + j0]       = v1;   // T1 row r
        *(float4*)&T2s[(127 - r0 - i) * 32 + j0] = v2;   // T2 row 127-r
    }
    __syncthreads();

    // ---- phase 2 ----
    const int f0 = rowg * 4;               // 4 f-rows per thread
    float C[4][4], S[4][4];
    #pragma unroll
    for (int i = 0; i < 4; ++i)
        #pragma unroll
        for (int l = 0; l < 4; ++l) { C[i][l] = 0.f; S[i][l] = 0.f; }

    for (int mm = 0; mm < 128; mm += 4) {
        float4 a[4];
        #pragma unroll
        for (int i = 0; i < 4; ++i)
            a[i] = *(const float4*)&cas[(f0 + i) * 128 + mm];         // cas[f][m..m+3]
        #pragma unroll
        for (int u = 0; u < 4; ++u) {
            const int m = mm + u;
            float4 t1 = *(const float4*)&T1s[m * 32 + j0];
            float4 t2 = *(const float4*)&T2s[m * 32 + j0];
            #pragma unroll
            for (int i = 0; i < 4; ++i) {
                float av = ((const float*)&a[i])[u];
                #pragma unroll
                for (int l = 0; l < 4; ++l) {
                    C[i][l] = fmaf(av, ((const float*)&t1)[l], C[i][l]);
                    S[i][l] = fmaf(av, ((const float*)&t2)[l], S[i][l]);
                }
            }
        }
    }

    // ---- epilogue: cosphi + corner extraction ----
    const size_t base = (size_t)img * 16384;
    #pragma unroll
    for (int i = 0; i < 4; ++i) {
        const int f = f0 + i;
        float4 o;
        #pragma unroll
        for (int l = 0; l < 4; ++l) {
            float Cv = C[i][l], Sv = S[i][l];
            float d = Cv * Cv + Sv * Sv;
            ((float*)&o)[l] = (d > 0.f) ? Cv * rsqrtf(d) : 1.0f;
        }
        *(float4*)&cosphi[base + f * 128 + G0 + j0] = o;
        if (G0 == 0 && j0 < 16) {
            if (f < 16) {
                #pragma unroll
                for (int l = 0; l < 4; ++l)
                    cp1[img * 256 + f * 16 + j0 + l] = C[i][l];
            } else if (f >= 112) {
                #pragma unroll
                for (int l = 0; l < 4; ++l)
                    cp2[img * 256 + (f - 112) * 16 + j0 + l] = C[i][l];
            }
        }
    }
}

// ---------------------------------------------------------------------------
// Kernel 2: corner complex-mul.
// od[b,o,x,y] = 0.5 * sum_i ( A*(W+Wn) + An*(W-Wn) )
// ---------------------------------------------------------------------------
__global__ __launch_bounds__(256) void k_corner(
    const float* __restrict__ cp1, const float* __restrict__ cp2,
    const float* __restrict__ w1,  const float* __restrict__ w2,
    float* __restrict__ od1, float* __restrict__ od2)
{
    const int c = blockIdx.y;
    const float* cp = c ? cp2 : cp1;
    const float* w  = c ? w2  : w1;
    float* od       = c ? od2 : od1;
    const int b = blockIdx.x >> 6, o = blockIdx.x & 63;
    const int t = threadIdx.x;
    const int xx = t >> 4, yy = t & 15;
    const int nx = (16 - xx) & 15, ny = (16 - yy) & 15;

    float acc = 0.f;
    #pragma unroll 4
    for (int i = 0; i < 64; ++i) {
        float A  = cp[((b * 64 + i) * 16 + xx) * 16 + yy];
        float An = cp[((b * 64 + i) * 16 + nx) * 16 + ny];
        float W  = w[((i * 64 + o) * 16 + xx) * 16 + yy];
        float Wn = w[((i * 64 + o) * 16 + nx) * 16 + ny];
        acc += A * (W + Wn) + An * (W - Wn);
    }
    od[((b * 64 + o) * 16 + xx) * 16 + yy] = 0.5f * acc;
}

// ---------------------------------------------------------------------------
// Kernel 3: sparse inverse DHT + final multiply (in place on d_out).
// ---------------------------------------------------------------------------
__global__ __launch_bounds__(256) void k_inv(
    const float* __restrict__ od1, const float* __restrict__ od2,
    const float* __restrict__ cas,
    float* __restrict__ out)
{
    __shared__ float odS[32 * 16];     // rows 0..15: od1, 16..31: od2
    __shared__ float casF[128 * 33];   // casF[s][j] = cas[s][ j<16 ? j : 96+j ]
    __shared__ float Rs[128 * 17];     // padded
    __shared__ float casG[16 * 128];   // cas rows 0..15

    const int img = blockIdx.x;
    const int t = threadIdx.x;

    odS[t]       = od1[img * 256 + t];
    odS[256 + t] = od2[img * 256 + t];
    #pragma unroll
    for (int k = 0; k < 16; ++k) {
        int idx = t + k * 256;
        int s = idx >> 5, j = idx & 31;
        int f = (j < 16) ? j : (96 + j);
        casF[s * 33 + j] = cas[s * 128 + f];
    }
    #pragma unroll
    for (int k = 0; k < 8; ++k) {
        int idx = t + k * 256;
        casG[idx] = cas[idx];
    }
    __syncthreads();

    {
        const int s1 = t >> 1, gb = (t & 1) * 8;
        float acc[8];
        #pragma unroll
        for (int l = 0; l < 8; ++l) acc[l] = 0.f;
        #pragma unroll 4
        for (int j = 0; j < 32; ++j) {
            float cf = casF[s1 * 33 + j];
            #pragma unroll
            for (int l = 0; l < 8; ++l)
                acc[l] = fmaf(cf, odS[j * 16 + gb + l], acc[l]);
        }
        #pragma unroll
        for (int l = 0; l < 8; ++l) Rs[s1 * 17 + gb + l] = acc[l];
    }
    __syncthreads();

    const float inv = 1.0f / 16384.0f;
    const int grp = t >> 5, lane = t & 31;
    const int s2 = lane * 4;
    for (int r = 0; r < 16; ++r) {
        const int s1 = grp * 16 + r;
        float4 acc = {0.f, 0.f, 0.f, 0.f};
        #pragma unroll
        for (int g = 0; g < 16; ++g) {
            float rv = Rs[s1 * 17 + g];
            float4 c4 = *(const float4*)&casG[g * 128 + s2];
            acc.x = fmaf(rv, c4.x, acc.x);
            acc.y = fmaf(rv, c4.y, acc.y);
            acc.z = fmaf(rv, c4.z, acc.z);
            acc.w = fmaf(rv, c4.w, acc.w);
        }
        size_t idx = (size_t)img * 16384 + (size_t)s1 * 128 + s2;
        float4 ph = *(const float4*)&out[idx];
        float4 res;
        res.x = acc.x * inv * ph.x;
        res.y = acc.y * inv * ph.y;
        res.z = acc.z * inv * ph.z;
        res.w = acc.w * inv * ph.w;
        *(float4*)&out[idx] = res;
    }
}

// ---------------------------------------------------------------------------
extern "C" void kernel_launch(void* const* d_in, const int* in_sizes, int n_in,
                              void* d_out, int out_size, void* d_ws, size_t ws_size,
                              hipStream_t stream) {
    (void)in_sizes; (void)n_in; (void)out_size; (void)ws_size;
    const float* x  = (const float*)d_in[0];
    const float* w1 = (const float*)d_in[1];
    const float* w2 = (const float*)d_in[2];
    float* out = (float*)d_out;
    float* ws  = (float*)d_ws;

    float* casf = ws;                // 16384
    float* cp1  = casf + 16384;      // 262144  (16*64*16*16)
    float* cp2  = cp1 + 262144;      // 262144
    float* od1  = cp2 + 262144;      // 262144
    float* od2  = od1 + 262144;      // 262144   total ~4.3 MB

    k_cas<<<dim3(128), dim3(128), 0, stream>>>(casf);
    k_dht<<<dim3(1024, 4), dim3(256), 0, stream>>>(x, casf, out, cp1, cp2);
    k_corner<<<dim3(1024, 2), dim3(256), 0, stream>>>(cp1, cp2, w1, w2, od1, od2);
    k_inv<<<dim3(1024), dim3(256), 0, stream>>>(od1, od2, casf, out);
}

// Round 7
// 166.108 us; speedup vs baseline: 2.2928x; 2.2928x over previous
//
#include <hip/hip_runtime.h>

typedef _Float16 f16;
typedef f16 f16x4 __attribute__((ext_vector_type(4)));
typedef f16 f16x8 __attribute__((ext_vector_type(8)));
typedef float f32x4 __attribute__((ext_vector_type(4)));

#define LSCALE 2048.0f          // lo-parts stored *2^11 (exact) to avoid f16 denormals
#define LINV   4.8828125e-4f    // 2^-11
#define XS 140                  // LDS stride (halfs) for X/W planes: 16 distinct banks on row walks
#define CS 137                  // LDS stride (floats) for CT/ST: odd -> conflict-free column walks

#define MFMA(A,B,C) __builtin_amdgcn_mfma_f32_16x16x32_f16(A, B, C, 0, 0, 0)

// ---------------------------------------------------------------------------
// Kernel 0: replicate the reference's fp32 cas table EXACTLY (round-2 lesson:
// a more accurate table FAILS — cosphi amplifies table mismatch), then build
// split-fp16 tables: A = cas, V[f][m] = cas[f][127-m]; each as hi + 2^11*lo.
// ---------------------------------------------------------------------------
__global__ void k_cas(float* __restrict__ casf,
                      f16* __restrict__ Ah, f16* __restrict__ Al,
                      f16* __restrict__ Vh, f16* __restrict__ Vl) {
    int f = blockIdx.x, m = threadIdx.x;
    const float SC = (float)(6.283185307179586 / 128.0);  // fp32(2*pi/128)
    float ang = SC * (float)(f * m);                      // fp32, unreduced
    double a = (double)ang;
    float v = (float)cos(a) + (float)sin(a);
    casf[f * 128 + m] = v;
    f16 h = (f16)v;
    f16 lo = (f16)((v - (float)h) * LSCALE);
    Ah[f * 128 + m] = h;
    Al[f * 128 + m] = lo;
    Vh[f * 128 + 127 - m] = h;    // V[f][127-m] = cas[f][m]
    Vl[f * 128 + 127 - m] = lo;
}

// ---------------------------------------------------------------------------
// Kernel 1 (MFMA): per image:
//   W1T[g][m] = sum_n A[g,n] X[m,n]   (= (X*A)[m,g]);  W2T from V
//   CT[g][f]  = sum_m W1T[g][m] A[f,m]  (= C[f,g]);    ST from V,W2T
//   cosphi = C*rsqrt(C^2+S^2) -> d_out; corners of C -> cp1/cp2
// Split-fp16: P*Q = Ph*Qh + 2^-11*(Pl'*Qh + Ph*Ql'), lo-parts prescaled 2^11.
// Fragment k-mapping: k = 32*ks + 8*(lane>>4) + e, identical for both MFMA
// operands -> any consistent bijection is exact (slot-pairing argument);
// C/D layout (col=lane&15, row=4*(lane>>4)+reg) is HW-verified.
// One block per image: X read from HBM exactly once (round-6 lesson).
// ---------------------------------------------------------------------------
__global__ __launch_bounds__(512, 2) void k_dht(
    const float* __restrict__ xg,
    const f16* __restrict__ Ah, const f16* __restrict__ Al,
    const f16* __restrict__ Vh, const f16* __restrict__ Vl,
    float* __restrict__ cosphi,
    float* __restrict__ cp1, float* __restrict__ cp2)
{
    __shared__ __align__(16) char smem[143360];
    f16* Xh  = (f16*)smem;               // [128][XS]
    f16* Xl  = (f16*)(smem + 35840);
    f16* W1h = (f16*)smem;               // reuse after pass 1
    f16* W1l = (f16*)(smem + 35840);
    f16* W2h = (f16*)(smem + 71680);
    f16* W2l = (f16*)(smem + 107520);
    float* CT = (float*)smem;            // [128][CS], reuse after pass 2
    float* ST = (float*)(smem + 70144);

    const int img = blockIdx.x;
    const float* X = xg + (size_t)img * 16384;
    const int t = threadIdx.x;
    const int lane = t & 63;
    const int wv = t >> 6;               // wave 0..7
    const int l15 = lane & 15;
    const int a4 = lane >> 4;            // 0..3

    // ---- stage X -> split fp16 planes in LDS (coalesced float4 reads) ----
    #pragma unroll
    for (int it = 0; it < 8; ++it) {
        int i = it * 512 + t;
        int r = i >> 5, c0 = (i & 31) * 4;
        float4 xv = *(const float4*)&X[r * 128 + c0];
        const float* xp = (const float*)&xv;
        f16x4 hv, lv;
        #pragma unroll
        for (int j = 0; j < 4; ++j) {
            f16 h = (f16)xp[j];
            hv[j] = h;
            lv[j] = (f16)((xp[j] - (float)h) * LSCALE);
        }
        *(f16x4*)&Xh[r * XS + c0] = hv;
        *(f16x4*)&Xl[r * XS + c0] = lv;
    }

    // ---- preload pass-1 table fragments (rows g = 16*wv + l15) ----
    f16x8 tAh[4], tAl[4], tVh[4], tVl[4];
    {
        const int row = 16 * wv + l15;
        #pragma unroll
        for (int ks = 0; ks < 4; ++ks) {
            int off = row * 128 + ks * 32 + 8 * a4;
            tAh[ks] = *(const f16x8*)&Ah[off];
            tAl[ks] = *(const f16x8*)&Al[off];
            tVh[ks] = *(const f16x8*)&Vh[off];
            tVl[ks] = *(const f16x8*)&Vl[off];
        }
    }
    __syncthreads();

    // ---- pass 1: W1T/W2T rows [16wv..16wv+16) over all m ----
    f32x4 w1hi[8], w1lo[8], w2hi[8], w2lo[8];
    #pragma unroll
    for (int i = 0; i < 8; ++i) {
        w1hi[i] = (f32x4){0.f,0.f,0.f,0.f}; w1lo[i] = (f32x4){0.f,0.f,0.f,0.f};
        w2hi[i] = (f32x4){0.f,0.f,0.f,0.f}; w2lo[i] = (f32x4){0.f,0.f,0.f,0.f};
    }
    #pragma unroll
    for (int mtp = 0; mtp < 4; ++mtp) {
        #pragma unroll
        for (int ks = 0; ks < 4; ++ks) {
            #pragma unroll
            for (int q = 0; q < 2; ++q) {
                const int mt = 2 * mtp + q;
                const int base = (16 * mt + l15) * XS + ks * 32 + 8 * a4;
                f16x4 h0 = *(const f16x4*)&Xh[base];
                f16x4 h1 = *(const f16x4*)&Xh[base + 4];
                f16x4 l0 = *(const f16x4*)&Xl[base];
                f16x4 l1 = *(const f16x4*)&Xl[base + 4];
                f16x8 xh = __builtin_shufflevector(h0, h1, 0,1,2,3,4,5,6,7);
                f16x8 xl = __builtin_shufflevector(l0, l1, 0,1,2,3,4,5,6,7);
                w1hi[mt] = MFMA(tAh[ks], xh, w1hi[mt]);
                w1lo[mt] = MFMA(tAl[ks], xh, w1lo[mt]);
                w1lo[mt] = MFMA(tAh[ks], xl, w1lo[mt]);
                w2hi[mt] = MFMA(tVh[ks], xh, w2hi[mt]);
                w2lo[mt] = MFMA(tVl[ks], xh, w2lo[mt]);
                w2lo[mt] = MFMA(tVh[ks], xl, w2lo[mt]);
            }
        }
    }
    __syncthreads();

    // ---- combine + split W to fp16 h/l planes (over X's LDS region) ----
    {
        const int g = 16 * wv + 4 * a4;
        #pragma unroll
        for (int mt = 0; mt < 8; ++mt) {
            const int m = 16 * mt + l15;
            #pragma unroll
            for (int r = 0; r < 4; ++r) {
                float v1 = w1hi[mt][r] + LINV * w1lo[mt][r];
                f16 h1 = (f16)v1;
                W1h[(g + r) * XS + m] = h1;
                W1l[(g + r) * XS + m] = (f16)((v1 - (float)h1) * LSCALE);
                float v2 = w2hi[mt][r] + LINV * w2lo[mt][r];
                f16 h2 = (f16)v2;
                W2h[(g + r) * XS + m] = h2;
                W2l[(g + r) * XS + m] = (f16)((v2 - (float)h2) * LSCALE);
            }
        }
    }
    __syncthreads();

    // ---- pass 2: waves 0-3 -> CT (ftiles 2w,2w+1), waves 4-7 -> ST ----
    const int cw  = wv >> 2;
    const int ft0 = 2 * (wv & 3);
    const f16* TBh = cw ? Vh : Ah;
    const f16* TBl = cw ? Vl : Al;
    const f16* Wph = cw ? W2h : W1h;
    const f16* Wpl = cw ? W2l : W1l;

    f16x8 tbh[2][4], tbl[2][4];
    #pragma unroll
    for (int ft = 0; ft < 2; ++ft) {
        const int row = 16 * (ft0 + ft) + l15;
        #pragma unroll
        for (int ks = 0; ks < 4; ++ks) {
            int off = row * 128 + ks * 32 + 8 * a4;
            tbh[ft][ks] = *(const f16x8*)&TBh[off];
            tbl[ft][ks] = *(const f16x8*)&TBl[off];
        }
    }

    f32x4 chi[2][8], clo[2][8];
    #pragma unroll
    for (int ft = 0; ft < 2; ++ft)
        #pragma unroll
        for (int i = 0; i < 8; ++i) {
            chi[ft][i] = (f32x4){0.f,0.f,0.f,0.f};
            clo[ft][i] = (f32x4){0.f,0.f,0.f,0.f};
        }
    #pragma unroll
    for (int gtp = 0; gtp < 4; ++gtp) {
        #pragma unroll
        for (int ks = 0; ks < 4; ++ks) {
            #pragma unroll
            for (int q = 0; q < 2; ++q) {
                const int gt = 2 * gtp + q;
                const int base = (16 * gt + l15) * XS + ks * 32 + 8 * a4;
                f16x4 h0 = *(const f16x4*)&Wph[base];
                f16x4 h1 = *(const f16x4*)&Wph[base + 4];
                f16x4 l0 = *(const f16x4*)&Wpl[base];
                f16x4 l1 = *(const f16x4*)&Wpl[base + 4];
                f16x8 wh = __builtin_shufflevector(h0, h1, 0,1,2,3,4,5,6,7);
                f16x8 wl = __builtin_shufflevector(l0, l1, 0,1,2,3,4,5,6,7);
                #pragma unroll
                for (int ft = 0; ft < 2; ++ft) {
                    chi[ft][gt] = MFMA(wh, tbh[ft][ks], chi[ft][gt]);
                    clo[ft][gt] = MFMA(wl, tbh[ft][ks], clo[ft][gt]);
                    clo[ft][gt] = MFMA(wh, tbl[ft][ks], clo[ft][gt]);
                }
            }
        }
    }
    __syncthreads();

    // ---- write CT/ST fp32 into LDS (over W region) ----
    {
        float* R = cw ? ST : CT;
        const int gg = 4 * a4;
        #pragma unroll
        for (int ft = 0; ft < 2; ++ft) {
            const int f = 16 * (ft0 + ft) + l15;
            #pragma unroll
            for (int gt = 0; gt < 8; ++gt)
                #pragma unroll
                for (int r = 0; r < 4; ++r)
                    R[(16 * gt + gg + r) * CS + f] = chi[ft][gt][r] + LINV * clo[ft][gt][r];
        }
    }
    __syncthreads();

    // ---- epilogue: cosphi + corners (coalesced global writes) ----
    const int g0 = 4 * (t & 31);
    const int fb = t >> 5;
    const size_t obase = (size_t)img * 16384;
    #pragma unroll
    for (int it = 0; it < 8; ++it) {
        const int f = fb + 16 * it;
        float4 o; float cv[4];
        #pragma unroll
        for (int i = 0; i < 4; ++i) {
            float C = CT[(g0 + i) * CS + f];
            float S = ST[(g0 + i) * CS + f];
            cv[i] = C;
            float d = C * C + S * S;
            ((float*)&o)[i] = (d > 0.f) ? C * rsqrtf(d) : 1.0f;
        }
        *(float4*)&cosphi[obase + f * 128 + g0] = o;
        if (g0 < 16) {
            if (f < 16)
                *(float4*)&cp1[img * 256 + f * 16 + g0] = *(float4*)cv;
            else if (f >= 112)
                *(float4*)&cp2[img * 256 + (f - 112) * 16 + g0] = *(float4*)cv;
        }
    }
}

// ---------------------------------------------------------------------------
// Kernel 2: corner complex-mul.  od[b,o,x,y] = 0.5*sum_i(A*(W+Wn)+An*(W-Wn))
// ---------------------------------------------------------------------------
__global__ __launch_bounds__(256) void k_corner(
    const float* __restrict__ cp1, const float* __restrict__ cp2,
    const float* __restrict__ w1,  const float* __restrict__ w2,
    float* __restrict__ od1, float* __restrict__ od2)
{
    const int c = blockIdx.y;
    const float* cp = c ? cp2 : cp1;
    const float* w  = c ? w2  : w1;
    float* od       = c ? od2 : od1;
    const int b = blockIdx.x >> 6, o = blockIdx.x & 63;
    const int t = threadIdx.x;
    const int xx = t >> 4, yy = t & 15;
    const int nx = (16 - xx) & 15, ny = (16 - yy) & 15;

    float acc = 0.f;
    #pragma unroll 4
    for (int i = 0; i < 64; ++i) {
        float A  = cp[((b * 64 + i) * 16 + xx) * 16 + yy];
        float An = cp[((b * 64 + i) * 16 + nx) * 16 + ny];
        float W  = w[((i * 64 + o) * 16 + xx) * 16 + yy];
        float Wn = w[((i * 64 + o) * 16 + nx) * 16 + ny];
        acc += A * (W + Wn) + An * (W - Wn);
    }
    od[((b * 64 + o) * 16 + xx) * 16 + yy] = 0.5f * acc;
}

// ---------------------------------------------------------------------------
// Kernel 3: sparse inverse DHT + final multiply (in place on d_out).
// ---------------------------------------------------------------------------
__global__ __launch_bounds__(256) void k_inv(
    const float* __restrict__ od1, const float* __restrict__ od2,
    const float* __restrict__ cas,
    float* __restrict__ out)
{
    __shared__ float odS[32 * 16];
    __shared__ float casF[128 * 33];
    __shared__ float Rs[128 * 17];
    __shared__ float casG[16 * 128];

    const int img = blockIdx.x;
    const int t = threadIdx.x;

    odS[t]       = od1[img * 256 + t];
    odS[256 + t] = od2[img * 256 + t];
    #pragma unroll
    for (int k = 0; k < 16; ++k) {
        int idx = t + k * 256;
        int s = idx >> 5, j = idx & 31;
        int f = (j < 16) ? j : (96 + j);
        casF[s * 33 + j] = cas[s * 128 + f];
    }
    #pragma unroll
    for (int k = 0; k < 8; ++k) {
        int idx = t + k * 256;
        casG[idx] = cas[idx];
    }
    __syncthreads();

    {
        const int s1 = t >> 1, gb = (t & 1) * 8;
        float acc[8];
        #pragma unroll
        for (int l = 0; l < 8; ++l) acc[l] = 0.f;
        #pragma unroll 4
        for (int j = 0; j < 32; ++j) {
            float cf = casF[s1 * 33 + j];
            #pragma unroll
            for (int l = 0; l < 8; ++l)
                acc[l] = fmaf(cf, odS[j * 16 + gb + l], acc[l]);
        }
        #pragma unroll
        for (int l = 0; l < 8; ++l) Rs[s1 * 17 + gb + l] = acc[l];
    }
    __syncthreads();

    const float inv = 1.0f / 16384.0f;
    const int grp = t >> 5, lane = t & 31;
    const int s2 = lane * 4;
    for (int r = 0; r < 16; ++r) {
        const int s1 = grp * 16 + r;
        float4 acc = {0.f, 0.f, 0.f, 0.f};
        #pragma unroll
        for (int g = 0; g < 16; ++g) {
            float rv = Rs[s1 * 17 + g];
            float4 c4 = *(const float4*)&casG[g * 128 + s2];
            acc.x = fmaf(rv, c4.x, acc.x);
            acc.y = fmaf(rv, c4.y, acc.y);
            acc.z = fmaf(rv, c4.z, acc.z);
            acc.w = fmaf(rv, c4.w, acc.w);
        }
        size_t idx = (size_t)img * 16384 + (size_t)s1 * 128 + s2;
        float4 ph = *(const float4*)&out[idx];
        float4 res;
        res.x = acc.x * inv * ph.x;
        res.y = acc.y * inv * ph.y;
        res.z = acc.z * inv * ph.z;
        res.w = acc.w * inv * ph.w;
        *(float4*)&out[idx] = res;
    }
}

// ---------------------------------------------------------------------------
extern "C" void kernel_launch(void* const* d_in, const int* in_sizes, int n_in,
                              void* d_out, int out_size, void* d_ws, size_t ws_size,
                              hipStream_t stream) {
    (void)in_sizes; (void)n_in; (void)out_size; (void)ws_size;
    const float* x  = (const float*)d_in[0];
    const float* w1 = (const float*)d_in[1];
    const float* w2 = (const float*)d_in[2];
    float* out = (float*)d_out;
    float* ws  = (float*)d_ws;

    float* casf = ws;                        // 16384 f32
    f16* Ah = (f16*)(ws + 16384);            // 16384 halfs each
    f16* Al = Ah + 16384;
    f16* Vh = Al + 16384;
    f16* Vl = Vh + 16384;
    float* cp1 = (float*)(Vl + 16384);       // 262144 f32 each
    float* cp2 = cp1 + 262144;
    float* od1 = cp2 + 262144;
    float* od2 = od1 + 262144;               // total ~4.4 MB

    k_cas<<<dim3(128), dim3(128), 0, stream>>>(casf, Ah, Al, Vh, Vl);
    k_dht<<<dim3(1024), dim3(512), 0, stream>>>(x, Ah, Al, Vh, Vl, out, cp1, cp2);
    k_corner<<<dim3(1024, 2), dim3(256), 0, stream>>>(cp1, cp2, w1, w2, od1, od2);
    k_inv<<<dim3(1024), dim3(256), 0, stream>>>(od1, od2, casf, out);
}